// Round 10
// baseline (70.734 us; speedup 1.0000x reference)
//
#include <hip/hip_runtime.h>

#define NPIX 9216          // C*H*W = 1*96*96
#define NROWS (NPIX + 1)   // 9217 rows in zonotope
#define ROW4 (NPIX / 4)    // 2304 f32x4 per row
#define EPSV 0.1f

#define SPT 3              // stores per thread in write kernel
#define BLKS_PER_ROW 3     // 2304 / (256*SPT)

typedef float f32x4 __attribute__((ext_vector_type(4)));

// ---------------------------------------------------------------------------
// Kernel 1: stream compaction + bias row.
//  - iv[row] = {pixel, bits(err)} for compacted rows 1..K, {-1,0} elsewhere
//  - out row 0 = clipped bias (elementwise from x; this block already owns x)
// Single block, 1024 threads; NPIX = 1024 * 9 exactly.
// ---------------------------------------------------------------------------
__global__ __launch_bounds__(1024) void prep_kernel(const float* __restrict__ x,
                                                    int2* __restrict__ iv,
                                                    f32x4* __restrict__ out) {
    __shared__ int wsum[16];
    const int tid  = threadIdx.x;
    const int lane = tid & 63;
    const int wid  = tid >> 6;
    const int base = tid * 9;

    for (int s = tid; s < NROWS; s += 1024) iv[s] = make_int2(-1, 0);

    float e_loc[9];
    int   c_loc[9];
    int   cnt = 0;
#pragma unroll
    for (int k = 0; k < 9; ++k) {
        const float xv     = x[base + k];
        const float r_low  = fmaxf(EPSV - xv, 0.0f) * 0.5f;
        const float r_high = fmaxf(xv - (1.0f - EPSV), 0.0f) * 0.5f;
        const float e      = EPSV - r_low - r_high;
        e_loc[k] = e;
        c_loc[k] = (e >= 0.0f) ? 1 : 0;
        cnt += c_loc[k];
    }

    // inclusive shuffle scan of per-thread counts within each wave
    int v = cnt;
#pragma unroll
    for (int off = 1; off < 64; off <<= 1) {
        const int t = __shfl_up(v, off, 64);
        if (lane >= off) v += t;
    }
    if (lane == 63) wsum[wid] = v;
    __syncthreads();   // also orders the -1 init before the scatter below

    int woff = 0;
#pragma unroll
    for (int w = 0; w < 16; ++w) woff += (w < wid) ? wsum[w] : 0;

    int slot = woff + v - cnt;     // exclusive prefix (0-based)
#pragma unroll
    for (int k = 0; k < 9; ++k) {
        if (c_loc[k]) {
            ++slot;                // 1-based compacted slot == output row
            iv[slot] = make_int2(base + k, __float_as_int(e_loc[k]));
        }
    }

    // bias row 0 (disjoint from write_kernel's rows 1..9216)
    const f32x4* x4 = reinterpret_cast<const f32x4*>(x);
#pragma unroll
    for (int it = 0; it < 3; ++it) {
        const int c4 = tid + it * 1024;
        if (c4 < ROW4) {
            const f32x4 xv = x4[c4];
            f32x4 o;
#pragma unroll
            for (int d = 0; d < 4; ++d) {
                const float vv = xv[d];
                o[d] = vv + fmaxf(EPSV - vv, 0.0f) * 0.5f
                          - fmaxf(vv - (1.0f - EPSV), 0.0f) * 0.5f;
            }
            out[c4] = o;
        }
    }
}

// ---------------------------------------------------------------------------
// Kernel 2: branch-free write of rows 1..9216. 27,648 blocks x 256 threads,
// 3 f32x4 stores per thread; each block owns a contiguous 12 KB third-of-row.
// Grid marches linearly through HBM (R9's proven pattern, 3x fewer WG
// dispatches). iv[row] is a block-uniform scalar load; unused rows (-1)
// never match -> stay zero.
// ---------------------------------------------------------------------------
__global__ __launch_bounds__(256) void write_kernel(const int2* __restrict__ iv,
                                                    f32x4* __restrict__ out) {
    const int bid = blockIdx.x;
    const int row = bid / BLKS_PER_ROW + 1;          // scalar magic-div
    const int sub = bid - (row - 1) * BLKS_PER_ROW;

    const int2 p  = iv[row];                         // block-uniform scalar load
    const float e = __int_as_float(p.y);

    f32x4* orow = out + (long long)row * ROW4 + sub * (256 * SPT) + threadIdx.x;
#pragma unroll
    for (int it = 0; it < SPT; ++it) {
        const int col = (sub * (256 * SPT) + it * 256 + threadIdx.x) * 4;
        f32x4 o;
        o.x = (p.x == col)     ? e : 0.0f;
        o.y = (p.x == col + 1) ? e : 0.0f;
        o.z = (p.x == col + 2) ? e : 0.0f;
        o.w = (p.x == col + 3) ? e : 0.0f;
        orow[it * 256] = o;
    }
}

extern "C" void kernel_launch(void* const* d_in, const int* in_sizes, int n_in,
                              void* d_out, int out_size, void* d_ws, size_t ws_size,
                              hipStream_t stream) {
    const float* x = (const float*)d_in[0];
    float* out = (float*)d_out;
    int2* iv = (int2*)d_ws;       // NROWS descriptors

    prep_kernel<<<1, 1024, 0, stream>>>(x, iv, (f32x4*)out);
    write_kernel<<<NPIX * BLKS_PER_ROW, 256, 0, stream>>>(iv, (f32x4*)out);
}

// Round 11
// 60.735 us; speedup vs baseline: 1.1646x; 1.1646x over previous
//
#include <hip/hip_runtime.h>

#define NPIX 9216          // C*H*W = 1*96*96
#define NROWS (NPIX + 1)   // 9217 rows in zonotope
#define ROW4 (NPIX / 4)    // 2304 f32x4 per row
#define EPSV 0.1f

typedef float f32x4 __attribute__((ext_vector_type(4)));

// ---------------------------------------------------------------------------
// Kernel 1: pure zero-fill of rows 1..9216. One f32x4 store per thread,
// 82,944 blocks x 256 threads, grid marches linearly through HBM.
// No loads, no branches, no dependencies — the exact fillBufferAligned
// structure (R9's one-store-per-thread pattern minus the iv scalar load).
// ---------------------------------------------------------------------------
__global__ __launch_bounds__(256) void fill_kernel(f32x4* __restrict__ out) {
    const f32x4 z = {0.0f, 0.0f, 0.0f, 0.0f};
    out[ROW4 + (long long)blockIdx.x * 256 + threadIdx.x] = z;
}

// ---------------------------------------------------------------------------
// Kernel 2 (after fill): single block, 1024 threads (R8's proven finisher):
//  - per-pixel err + cond, block-wide shuffle scan (stream compaction)
//  - scatter: out[slot*NPIX + pixel] = err  (~3.7K dword stores)
//  - row 0 = clipped bias, coalesced f32x4 stores
// Rows past the compacted count keep the fill's zeros.
// ---------------------------------------------------------------------------
__global__ __launch_bounds__(1024) void finish_kernel(const float* __restrict__ x,
                                                      float* __restrict__ out) {
    __shared__ int wsum[16];
    const int tid  = threadIdx.x;
    const int lane = tid & 63;
    const int wid  = tid >> 6;
    const int base = tid * 9;      // 9 contiguous pixels per thread

    float e_loc[9];
    int   c_loc[9];
    int   cnt = 0;
#pragma unroll
    for (int k = 0; k < 9; ++k) {
        const float xv     = x[base + k];
        const float r_low  = fmaxf(EPSV - xv, 0.0f) * 0.5f;
        const float r_high = fmaxf(xv - (1.0f - EPSV), 0.0f) * 0.5f;
        const float e      = EPSV - r_low - r_high;
        e_loc[k] = e;
        c_loc[k] = (e >= 0.0f) ? 1 : 0;
        cnt += c_loc[k];
    }

    // inclusive shuffle scan of per-thread counts within each wave
    int v = cnt;
#pragma unroll
    for (int off = 1; off < 64; off <<= 1) {
        const int t = __shfl_up(v, off, 64);
        if (lane >= off) v += t;
    }
    if (lane == 63) wsum[wid] = v;
    __syncthreads();

    int woff = 0;
#pragma unroll
    for (int w = 0; w < 16; ++w) woff += (w < wid) ? wsum[w] : 0;

    int slot = woff + v - cnt;     // exclusive prefix (0-based)
#pragma unroll
    for (int k = 0; k < 9; ++k) {
        if (c_loc[k]) {
            ++slot;                // 1-based compacted slot == output row
            out[(long long)slot * NPIX + (base + k)] = e_loc[k];
        }
    }

    // row 0: clipped bias, coalesced f32x4
    const f32x4* x4 = reinterpret_cast<const f32x4*>(x);
    f32x4* o4 = reinterpret_cast<f32x4*>(out);
#pragma unroll
    for (int it = 0; it < 3; ++it) {
        const int c4 = tid + it * 1024;
        if (c4 < ROW4) {
            const f32x4 xv = x4[c4];
            f32x4 o;
#pragma unroll
            for (int d = 0; d < 4; ++d) {
                const float vv = xv[d];
                o[d] = vv + fmaxf(EPSV - vv, 0.0f) * 0.5f
                          - fmaxf(vv - (1.0f - EPSV), 0.0f) * 0.5f;
            }
            o4[c4] = o;
        }
    }
}

extern "C" void kernel_launch(void* const* d_in, const int* in_sizes, int n_in,
                              void* d_out, int out_size, void* d_ws, size_t ws_size,
                              hipStream_t stream) {
    const float* x = (const float*)d_in[0];
    float* out = (float*)d_out;

    fill_kernel<<<NPIX * 9, 256, 0, stream>>>((f32x4*)out);   // rows 1..9216
    finish_kernel<<<1, 1024, 0, stream>>>(x, out);
}